// Round 8
// baseline (102966.492 us; speedup 1.0000x reference)
//
#include <hip/hip_runtime.h>
#include <math.h>

#define TT    100000
#define HH    74
#define G4    296          // 4*H gate rows per layer
#define KP    80           // K padded 74 -> 80
#define QW    20           // per-thread K slice (quarter of KP)
#define NGRP  60           // groups of 5 rows (300 >= 296)
#define SLOT  80           // h-ring / LDS h slot stride (floats)
#define ZSLOT 304          // zx-ring / LDS zx slot stride
#define NT    384          // w0-w3 rows (240 active) | w4 prefetch | w5 publish+cell
#define WPRE  256
#define WPUB  320

typedef float f4 __attribute__((ext_vector_type(4)));

#define ALD(p)    __hip_atomic_load((p),  __ATOMIC_RELAXED, __HIP_MEMORY_SCOPE_AGENT)
#define ALDA(p)   __hip_atomic_load((p),  __ATOMIC_ACQUIRE, __HIP_MEMORY_SCOPE_AGENT)
#define AST(p,v)  __hip_atomic_store((p),(v),__ATOMIC_RELAXED, __HIP_MEMORY_SCOPE_AGENT)
#define ASTR(p,v) __hip_atomic_store((p),(v),__ATOMIC_RELEASE, __HIP_MEMORY_SCOPE_AGENT)

// lgkm-only barrier: keeps ring loads/stores in flight across steps (round-7 win)
#define BAR() asm volatile("s_waitcnt lgkmcnt(0)\n\ts_barrier" ::: "memory")

__global__ void init_ctrl(unsigned* ctrl) {
    ctrl[threadIdx.x] = 0u;   // 256 dwords; ws is poisoned 0xAA each launch
}

__launch_bounds__(NT, 2)     // 256-VGPR budget; ~150 needed (100 pinned weights)
__global__ void lstm_pipe6(const float* __restrict__ seasons,
                           const float* __restrict__ W_ih,
                           const float* __restrict__ W_hh,
                           const float* __restrict__ b_ih,
                           const float* __restrict__ b_hh,
                           const float* __restrict__ W_lin,
                           const float* __restrict__ b_lin,
                           float* __restrict__ out,
                           unsigned* ctrl,
                           float* zbase, float* hbase, int CZ, int CH)
{
    const int  bid = blockIdx.x;      // 0..5: 2l = A_l (zx), 2l+1 = B_l (recurrence)
    const int  l   = bid >> 1;
    const bool isA = (bid & 1) == 0;
    const int  tid = threadIdx.x;

    __shared__ __align__(16) float sIn[2][SLOT];   // A: layer input dbuf
    __shared__ __align__(16) float sZ[2][ZSLOT];   // A: zx out-dbuf | B: zx in-dbuf
    __shared__ __align__(16) float sH[SLOT];       // B: h(t-1)
    __shared__ float sG[ZSLOT];                    // B: activated gates (pad to 304)

    unsigned* cnt_out = ctrl + bid * 32;
    unsigned* cnt_in  = ctrl + (bid > 0 ? (bid - 1) * 32 : 0);
    unsigned* cnt_dn  = ctrl + (bid < 5 ? (bid + 1) * 32 : 0);

    float* zring     = zbase + (size_t)l * CZ * ZSLOT;
    float* hring_out = hbase + (size_t)l * CH * SLOT;
    float* hring_in  = (l > 0) ? hbase + (size_t)(l-1) * CH * SLOT : (float*)0;

    // ---- LDS init: h(-1)=0 incl pad; sIn fully zeroed (pads stay 0 forever) ----
    if (tid < SLOT) { sH[tid] = 0.0f; sIn[0][tid] = 0.0f; sIn[1][tid] = 0.0f; }

    // ---- row mapping: 5 rows/thread, K-quarter slice; lane quartet = 4 quarters ----
    const bool isRowT = (tid < WPRE);
    const int  g  = tid >> 2;                    // group 0..63 (active < 60)
    const int  q  = tid & 3;                     // K-quarter
    const int  gg = (g < NGRP) ? g : NGRP - 1;   // clamp for safe loads

    // 25 named f4 = 100 weight floats/thread, asm-pinned (round-6 proven mechanism)
#define DW(n) f4 n = {0.f,0.f,0.f,0.f}
    DW(w00);DW(w01);DW(w02);DW(w03);DW(w04); DW(w10);DW(w11);DW(w12);DW(w13);DW(w14);
    DW(w20);DW(w21);DW(w22);DW(w23);DW(w24); DW(w30);DW(w31);DW(w32);DW(w33);DW(w34);
    DW(w40);DW(w41);DW(w42);DW(w43);DW(w44);
#undef DW
    float biasA = 0.f, biasB = 0.f;

    if (isRowT) {
        const float* Wm = (isA ? W_ih : W_hh) + (size_t)l * G4 * HH;
#define LDW(V, I, S) { \
        int r_ = 5*gg + (I); if (r_ > G4-1) r_ = G4-1; \
        float sc_ = (r_ >= 2*HH && r_ < 3*HH) ? 2.0f : 1.0f;  /* fold tanh 2x */ \
        const float* p_ = Wm + (size_t)r_ * HH; \
        int k0_ = QW*q + 4*(S); \
        int ka_ = k0_;   if (ka_ > HH-1) ka_ = HH-1;   /* clamped addr; */ \
        int kb_ = k0_+1; if (kb_ > HH-1) kb_ = HH-1;   /* operand pad is 0 */ \
        int kc_ = k0_+2; if (kc_ > HH-1) kc_ = HH-1; \
        int kd_ = k0_+3; if (kd_ > HH-1) kd_ = HH-1; \
        V[0] = sc_*p_[ka_]; V[1] = sc_*p_[kb_]; V[2] = sc_*p_[kc_]; V[3] = sc_*p_[kd_]; }
        LDW(w00,0,0) LDW(w01,0,1) LDW(w02,0,2) LDW(w03,0,3) LDW(w04,0,4)
        LDW(w10,1,0) LDW(w11,1,1) LDW(w12,1,2) LDW(w13,1,3) LDW(w14,1,4)
        LDW(w20,2,0) LDW(w21,2,1) LDW(w22,2,2) LDW(w23,2,3) LDW(w24,2,4)
        LDW(w30,3,0) LDW(w31,3,1) LDW(w32,3,2) LDW(w33,3,3) LDW(w34,3,4)
        LDW(w40,4,0) LDW(w41,4,1) LDW(w42,4,2) LDW(w43,4,3) LDW(w44,4,4)
#undef LDW
        asm volatile("" : "+v"(w00),"+v"(w01),"+v"(w02),"+v"(w03),"+v"(w04),
                          "+v"(w10),"+v"(w11),"+v"(w12),"+v"(w13),"+v"(w14),
                          "+v"(w20),"+v"(w21),"+v"(w22),"+v"(w23),"+v"(w24));
        asm volatile("" : "+v"(w30),"+v"(w31),"+v"(w32),"+v"(w33),"+v"(w34),
                          "+v"(w40),"+v"(w41),"+v"(w42),"+v"(w43),"+v"(w44));
        if (isA) {   // bias for the rows this lane OWNS after reduce-scatter
            int r0 = 5*gg + q; if (r0 > G4-1) r0 = G4-1;
            float s0 = (r0 >= 2*HH && r0 < 3*HH) ? 2.0f : 1.0f;
            biasA = s0 * (b_ih[l*G4 + r0] + b_hh[l*G4 + r0]);
            if (q == 3) {
                int r4 = 5*gg + 4; if (r4 > G4-1) r4 = G4-1;
                float s4 = (r4 >= 2*HH && r4 < 3*HH) ? 2.0f : 1.0f;
                biasB = s4 * (b_ih[l*G4 + r4] + b_hh[l*G4 + r4]);
            }
        }
    }

    float wl0 = 0.f, wl1 = 0.f, blin = 0.f;
    if (bid == 5 && tid >= WPUB) {               // final linear on publish wave
        int lane = tid - WPUB;
        wl0 = W_lin[lane];
        wl1 = (lane < HH-64) ? W_lin[64 + lane] : 0.0f;
        blin = b_lin[0];
    }

    __syncthreads();

    // ---- prologue (prefetch wave): LDS[0]=slot0; regset A=slot1, B=slot2 ----
    float irA0=0.f, irA1=0.f, irB0=0.f, irB1=0.f;
    float zA0=0.f,zA1=0.f,zA2=0.f,zA3=0.f,zA4=0.f;
    float zB0=0.f,zB1=0.f,zB2=0.f,zB3=0.f,zB4=0.f;
    unsigned cin = 0, cons = 0;
    if (tid >= WPRE && tid < WPUB) {
        const int lane = tid - WPRE;
        if (isA) {
            if (l == 0) {
                sIn[0][lane] = seasons[lane];
                if (lane < HH-64) sIn[0][64+lane] = seasons[64+lane];
                irA0 = seasons[HH + lane];
                if (lane < HH-64) irA1 = seasons[HH + 64 + lane];
                irB0 = seasons[2*HH + lane];
                if (lane < HH-64) irB1 = seasons[2*HH + 64 + lane];
            } else {
                do { cin = ALDA(cnt_in); } while (cin < 3u);
                sIn[0][lane] = ALD(hring_in + lane);
                if (lane < HH-64) sIn[0][64+lane] = ALD(hring_in + 64 + lane);
                const float* r1 = hring_in + (size_t)(1 % CH) * SLOT;
                irA0 = ALD(r1 + lane);
                if (lane < HH-64) irA1 = ALD(r1 + 64 + lane);
                const float* r2 = hring_in + (size_t)(2 % CH) * SLOT;
                irB0 = ALD(r2 + lane);
                if (lane < HH-64) irB1 = ALD(r2 + 64 + lane);
            }
        } else {
            do { cin = ALDA(cnt_in); } while (cin < 3u);
            sZ[0][lane]       = ALD(zring + lane);
            sZ[0][64 + lane]  = ALD(zring + 64 + lane);
            sZ[0][128 + lane] = ALD(zring + 128 + lane);
            sZ[0][192 + lane] = ALD(zring + 192 + lane);
            if (lane < G4-256) sZ[0][256 + lane] = ALD(zring + 256 + lane);
            const float* r1 = zring + (size_t)(1 % CZ) * ZSLOT;
            zA0 = ALD(r1 + lane);        zA1 = ALD(r1 + 64 + lane);
            zA2 = ALD(r1 + 128 + lane);  zA3 = ALD(r1 + 192 + lane);
            zA4 = (lane < G4-256) ? ALD(r1 + 256 + lane) : 0.0f;
            const float* r2 = zring + (size_t)(2 % CZ) * ZSLOT;
            zB0 = ALD(r2 + lane);        zB1 = ALD(r2 + 64 + lane);
            zB2 = ALD(r2 + 128 + lane);  zB3 = ALD(r2 + 192 + lane);
            zB4 = (lane < G4-256) ? ALD(r2 + 256 + lane) : 0.0f;
        }
    }
    __syncthreads();

    float c0 = 0.0f, c1 = 0.0f;     // cell state (publish wave lanes; lane<10 holds 2)

#define ACC(A_, W_, V_) A_ = fmaf(W_[0],V_[0], fmaf(W_[1],V_[1], fmaf(W_[2],V_[2], fmaf(W_[3],V_[3], A_))))

#define STEP(T, IR0, IR1, Z0, Z1, Z2, Z3, Z4)                                     \
{                                                                                 \
    const int b_ = (T) & 1;                                                       \
    if (isRowT) {                                                                 \
        const f4* vv = ((const f4*)(isA ? sIn[b_] : sH)) + q*(QW/4);              \
        f4 v0=vv[0], v1=vv[1], v2=vv[2], v3=vv[3], v4=vv[4];                      \
        float a0=0.f,a1=0.f,a2=0.f,a3=0.f,a4=0.f;                                 \
        ACC(a0,w00,v0); ACC(a0,w01,v1); ACC(a0,w02,v2); ACC(a0,w03,v3); ACC(a0,w04,v4); \
        ACC(a1,w10,v0); ACC(a1,w11,v1); ACC(a1,w12,v2); ACC(a1,w13,v3); ACC(a1,w14,v4); \
        ACC(a2,w20,v0); ACC(a2,w21,v1); ACC(a2,w22,v2); ACC(a2,w23,v3); ACC(a2,w24,v4); \
        ACC(a3,w30,v0); ACC(a3,w31,v1); ACC(a3,w32,v2); ACC(a3,w33,v3); ACC(a3,w34,v4); \
        ACC(a4,w40,v0); ACC(a4,w41,v1); ACC(a4,w42,v2); ACC(a4,w43,v3); ACC(a4,w44,v4); \
        /* reduce-scatter over the quartet: lane q ends with row 5g+q total */    \
        float s0_ = (q&1) ? a0 : a1;  float r0_ = __shfl_xor(s0_, 1, 64);         \
        float s1_ = (q&1) ? a2 : a3;  float r1_ = __shfl_xor(s1_, 1, 64);         \
        float u0_ = ((q&1) ? a1 : a0) + r0_;                                      \
        float u1_ = ((q&1) ? a3 : a2) + r1_;                                      \
        float c4_ = a4 + __shfl_xor(a4, 1, 64);                                   \
        float s2_ = (q&2) ? u0_ : u1_; float r2_ = __shfl_xor(s2_, 2, 64);        \
        float tot  = ((q&2) ? u1_ : u0_) + r2_;                                   \
        float tot4 = c4_ + __shfl_xor(c4_, 2, 64);    /* row 5g+4 (all lanes) */  \
        const int r0i = 5*g + q, r4i = 5*g + 4;                                   \
        if (isA) {                                                                \
            if (g < NGRP) sZ[b_][r0i] = tot + biasA;                              \
            if (q == 3 && g < NGRP) sZ[b_][r4i] = tot4 + biasB;                   \
        } else {                                                                  \
            float zx_ = (g < NGRP) ? sZ[b_][r0i] : 0.0f;                          \
            float t_  = tot + zx_;                                                \
            float sg_ = __builtin_amdgcn_rcpf(1.0f + __expf(-t_));                \
            float gt_ = (r0i >= 2*HH && r0i < 3*HH) ? fmaf(2.f,sg_,-1.f) : sg_;   \
            if (g < NGRP) sG[r0i] = gt_;                                          \
            if (q == 3 && g < NGRP) {                                             \
                float t4_  = tot4 + sZ[b_][r4i];                                  \
                float sg4_ = __builtin_amdgcn_rcpf(1.0f + __expf(-t4_));          \
                sG[r4i] = (r4i >= 2*HH && r4i < 3*HH) ? fmaf(2.f,sg4_,-1.f) : sg4_; \
            }                                                                     \
        }                                                                         \
    } else if (tid < WPUB) {  /* prefetch wave: depth-2 pipelined ring loads */   \
        const int lane = tid - WPRE;                                              \
        const int nb_ = ((T) + 1) & 1;                                            \
        int s_ = (T) + 3; if (s_ > TT-1) s_ = TT-1;                               \
        unsigned need_ = (unsigned)(s_ + 1); if (need_ > TT) need_ = TT;          \
        if (isA) {                                                                \
            sIn[nb_][lane] = IR0;                                                 \
            if (lane < HH-64) sIn[nb_][64+lane] = IR1;                            \
            if (l == 0) {                                                         \
                const float* xs_ = seasons + (size_t)s_ * HH;                     \
                IR0 = xs_[lane];                                                  \
                if (lane < HH-64) IR1 = xs_[64+lane];                             \
            } else {                                                              \
                if (cin < need_) { do { cin = ALDA(cnt_in); } while (cin < need_); } \
                const float* rs_ = hring_in + (size_t)(s_ % CH) * SLOT;           \
                IR0 = ALD(rs_ + lane);                                            \
                if (lane < HH-64) IR1 = ALD(rs_ + 64 + lane);                     \
                cin = ALD(cnt_in);                                                \
            }                                                                     \
        } else {                                                                  \
            sZ[nb_][lane] = Z0; sZ[nb_][64+lane] = Z1;                            \
            sZ[nb_][128+lane] = Z2; sZ[nb_][192+lane] = Z3;                       \
            if (lane < G4-256) sZ[nb_][256+lane] = Z4;                            \
            if (cin < need_) { do { cin = ALDA(cnt_in); } while (cin < need_); }  \
            const float* rs_ = zring + (size_t)(s_ % CZ) * ZSLOT;                 \
            Z0 = ALD(rs_ + lane); Z1 = ALD(rs_ + 64 + lane);                      \
            Z2 = ALD(rs_ + 128 + lane); Z3 = ALD(rs_ + 192 + lane);               \
            if (lane < G4-256) Z4 = ALD(rs_ + 256 + lane);                        \
            cin = ALD(cnt_in);                                                    \
        }                                                                         \
    } else {  /* publish wave: deferred release + stores (no in-step drain) */    \
        const int lane = tid - WPUB;                                              \
        if ((T) > 0) {                                                            \
            if (lane == 0) ASTR(cnt_out, (unsigned)((T)-1));  /* covers <=T-2 */  \
            if (isA) {                                                            \
                while ((long)((T)-1) - (long)cons > (long)(CZ - 8))               \
                    cons = ALD(cnt_dn);                                           \
                const int ob_ = ((T)-1) & 1;                                      \
                float x0_=sZ[ob_][lane],      x1_=sZ[ob_][64+lane];               \
                float x2_=sZ[ob_][128+lane],  x3_=sZ[ob_][192+lane];              \
                float x4_=(lane < G4-256) ? sZ[ob_][256+lane] : 0.0f;             \
                float* rp_ = zring + (size_t)(((T)-1) % CZ) * ZSLOT;              \
                AST(rp_ + lane, x0_);        AST(rp_ + 64 + lane, x1_);           \
                AST(rp_ + 128 + lane, x2_);  AST(rp_ + 192 + lane, x3_);          \
                if (lane < G4-256) AST(rp_ + 256 + lane, x4_);                    \
            } else if (l < 2) {                                                   \
                while ((long)((T)-1) - (long)cons > (long)(CH - 8))               \
                    cons = ALD(cnt_dn);                                           \
                float h0_ = sH[lane];                                             \
                float h1_ = (lane < HH-64) ? sH[64+lane] : 0.0f;                  \
                float* rp_ = hring_out + (size_t)(((T)-1) % CH) * SLOT;           \
                AST(rp_ + lane, h0_);                                             \
                if (lane < HH-64) AST(rp_ + 64 + lane, h1_);                      \
            } else {                                                              \
                float p_ = wl0 * sH[lane];                                        \
                if (lane < HH-64) p_ += wl1 * sH[64 + lane];                      \
                p_ += __shfl_xor(p_, 32, 64); p_ += __shfl_xor(p_, 16, 64);       \
                p_ += __shfl_xor(p_,  8, 64); p_ += __shfl_xor(p_,  4, 64);       \
                p_ += __shfl_xor(p_,  2, 64); p_ += __shfl_xor(p_,  1, 64);       \
                if (lane == 0) out[(T)-1] = fmaxf(p_ + blin, 0.0f);               \
            }                                                                     \
        }                                                                         \
    }                                                                             \
    BAR();                                                                        \
    if (!isA) {                                                                   \
        if (tid >= WPUB) {   /* cell update on publish wave */                    \
            const int u_ = tid - WPUB;                                            \
            float iv_=sG[u_], fv_=sG[HH+u_], gv_=sG[2*HH+u_], ov_=sG[3*HH+u_];    \
            c0 = fmaf(fv_, c0, iv_ * gv_);                                        \
            float e0_ = __expf(-2.0f * fabsf(c0));                                \
            sH[u_] = ov_ * copysignf((1.0f-e0_)*__builtin_amdgcn_rcpf(1.0f+e0_), c0); \
            if (u_ < HH-64) {                                                     \
                const int u2_ = 64 + u_;                                          \
                float iw_=sG[u2_], fw_=sG[HH+u2_], gw_=sG[2*HH+u2_], ow_=sG[3*HH+u2_]; \
                c1 = fmaf(fw_, c1, iw_ * gw_);                                    \
                float e1_ = __expf(-2.0f * fabsf(c1));                            \
                sH[u2_] = ow_ * copysignf((1.0f-e1_)*__builtin_amdgcn_rcpf(1.0f+e1_), c1); \
            }                                                                     \
        }                                                                         \
        BAR();                                                                    \
    }                                                                             \
}

    for (int t = 0; t < TT; t += 2) {       // TT even: exact
        STEP(t,     irA0, irA1, zA0, zA1, zA2, zA3, zA4)
        STEP(t + 1, irB0, irB1, zB0, zB1, zB2, zB3, zB4)
    }
#undef STEP
#undef ACC

    // ---- epilogue: publish data(TT-1), final release = TT ----
    if (tid >= WPUB) {
        const int lane = tid - WPUB;
        if (isA) {
            const int ob = (TT-1) & 1;
            float x0=sZ[ob][lane],      x1=sZ[ob][64+lane];
            float x2=sZ[ob][128+lane],  x3=sZ[ob][192+lane];
            float x4=(lane < G4-256) ? sZ[ob][256+lane] : 0.0f;
            float* rp = zring + (size_t)((TT-1) % CZ) * ZSLOT;
            AST(rp + lane, x0);        AST(rp + 64 + lane, x1);
            AST(rp + 128 + lane, x2);  AST(rp + 192 + lane, x3);
            if (lane < G4-256) AST(rp + 256 + lane, x4);
            if (lane == 0) ASTR(cnt_out, (unsigned)TT);
        } else if (l < 2) {
            float h0 = sH[lane];
            float h1 = (lane < HH-64) ? sH[64+lane] : 0.0f;
            float* rp = hring_out + (size_t)((TT-1) % CH) * SLOT;
            AST(rp + lane, h0);
            if (lane < HH-64) AST(rp + 64 + lane, h1);
            if (lane == 0) ASTR(cnt_out, (unsigned)TT);
        } else {
            float p = wl0 * sH[lane];
            if (lane < HH-64) p += wl1 * sH[64 + lane];
            p += __shfl_xor(p, 32, 64); p += __shfl_xor(p, 16, 64);
            p += __shfl_xor(p,  8, 64); p += __shfl_xor(p,  4, 64);
            p += __shfl_xor(p,  2, 64); p += __shfl_xor(p,  1, 64);
            if (lane == 0) out[TT-1] = fmaxf(p + blin, 0.0f);
            if (lane == 0) ASTR(cnt_out, (unsigned)TT);
        }
    }
}

extern "C" void kernel_launch(void* const* d_in, const int* in_sizes, int n_in,
                              void* d_out, int out_size, void* d_ws, size_t ws_size,
                              hipStream_t stream)
{
    (void)in_sizes; (void)n_in; (void)out_size;
    const float* seasons = (const float*)d_in[0];
    const float* W_ih  = (const float*)d_in[1];
    const float* W_hh  = (const float*)d_in[2];
    const float* b_ih  = (const float*)d_in[3];
    const float* b_hh  = (const float*)d_in[4];
    const float* W_lin = (const float*)d_in[5];
    const float* b_lin = (const float*)d_in[6];
    float* out = (float*)d_out;

    unsigned* ctrl = (unsigned*)d_ws;
    float* zbase = (float*)((char*)d_ws + 4096);
    long avail = ((long)ws_size - 4096) / 4;       // floats available
    int CZ = 256, CH = 1024;
    while ((3L*CZ*ZSLOT + 2L*CH*SLOT) > avail && CZ > 16) { CZ >>= 1; CH >>= 1; }
    if (CZ < 16) CZ = 16;
    if (CH < 16) CH = 16;
    float* hbase = zbase + 3L * CZ * ZSLOT;

    hipLaunchKernelGGL(init_ctrl, dim3(1), dim3(256), 0, stream, ctrl);
    hipLaunchKernelGGL(lstm_pipe6, dim3(6), dim3(NT), 0, stream,
                       seasons, W_ih, W_hh, b_ih, b_hh, W_lin, b_lin,
                       out, ctrl, zbase, hbase, CZ, CH);
}